// Round 1
// baseline (111.155 us; speedup 1.0000x reference)
//
#include <hip/hip_runtime.h>
#include <hip/hip_bf16.h>

#define B_ROWS 4096
#define C_CLS  1000
#define D_DIM  2048
#define NPAD   1024

typedef __attribute__((ext_vector_type(8))) short s16x8;
typedef __attribute__((ext_vector_type(4))) float f32x4;

__device__ __forceinline__ unsigned short f2bf(float f) {
    __hip_bfloat16 h = __float2bfloat16(f);
    unsigned short u;
    __builtin_memcpy(&u, &h, 2);
    return u;
}

// Kernel 1: W (1000x2048 fp32) -> Wb (1024x2048 bf16, padded rows zero) + sq_w fp32
__global__ __launch_bounds__(256) void prep_kernel(const float* __restrict__ W,
                                                   unsigned short* __restrict__ Wb,
                                                   float* __restrict__ sqw) {
    const int row = blockIdx.x;
    const int tid = threadIdx.x;
    unsigned short* wrow = Wb + (size_t)row * D_DIM;
    if (row >= C_CLS) {
        uint4 z; z.x = z.y = z.z = z.w = 0u;
        *reinterpret_cast<uint4*>(wrow + tid * 8) = z;
        if (tid == 0) sqw[row] = 0.f;
        return;
    }
    const float* wr = W + (size_t)row * D_DIM;
    float4 x0 = *reinterpret_cast<const float4*>(wr + tid * 8);
    float4 x1 = *reinterpret_cast<const float4*>(wr + tid * 8 + 4);
    float s = x0.x * x0.x + x0.y * x0.y + x0.z * x0.z + x0.w * x0.w
            + x1.x * x1.x + x1.y * x1.y + x1.z * x1.z + x1.w * x1.w;
    union { unsigned short u[8]; uint4 v; } pk;
    pk.u[0] = f2bf(x0.x); pk.u[1] = f2bf(x0.y); pk.u[2] = f2bf(x0.z); pk.u[3] = f2bf(x0.w);
    pk.u[4] = f2bf(x1.x); pk.u[5] = f2bf(x1.y); pk.u[6] = f2bf(x1.z); pk.u[7] = f2bf(x1.w);
    *reinterpret_cast<uint4*>(wrow + tid * 8) = pk.v;
#pragma unroll
    for (int off = 32; off > 0; off >>= 1) s += __shfl_down(s, off);
    __shared__ float sv[4];
    const int lane = tid & 63, wid = tid >> 6;
    if (lane == 0) sv[wid] = s;
    __syncthreads();
    if (tid == 0) sqw[row] = sv[0] + sv[1] + sv[2] + sv[3];
}

// Kernel 2: dist[a][c] = k * sqrt(max(sq[a]+sq[c]-2*Wb[a].Wb[c], 0))
// Block: 256 thr (4 waves), block tile 64x64, wave tile 32x32 (2x2 MFMA 16x16x32)
__global__ __launch_bounds__(256) void dist_kernel(const unsigned short* __restrict__ Wb,
                                                   const float* __restrict__ sqw,
                                                   const float* __restrict__ Kin,
                                                   float* __restrict__ dist) {
    const int tid  = threadIdx.x;
    const int lane = tid & 63;
    const int wid  = tid >> 6;       // 0..3
    const int wm   = wid >> 1;       // 0..1
    const int wn   = wid & 1;        // 0..1
    const int l16  = lane & 15;
    const int quad = lane >> 4;      // 0..3
    const int base_m = blockIdx.y * 64 + wm * 32;
    const int base_n = blockIdx.x * 64 + wn * 32;

    f32x4 acc00 = {0.f, 0.f, 0.f, 0.f};
    f32x4 acc01 = {0.f, 0.f, 0.f, 0.f};
    f32x4 acc10 = {0.f, 0.f, 0.f, 0.f};
    f32x4 acc11 = {0.f, 0.f, 0.f, 0.f};

    const unsigned short* arow0 = Wb + (size_t)(base_m + l16) * D_DIM;
    const unsigned short* arow1 = Wb + (size_t)(base_m + 16 + l16) * D_DIM;
    const unsigned short* brow0 = Wb + (size_t)(base_n + l16) * D_DIM;
    const unsigned short* brow1 = Wb + (size_t)(base_n + 16 + l16) * D_DIM;

    for (int k = 0; k < D_DIM; k += 32) {
        const int kk = k + quad * 8;
        s16x8 a0 = *reinterpret_cast<const s16x8*>(arow0 + kk);
        s16x8 a1 = *reinterpret_cast<const s16x8*>(arow1 + kk);
        s16x8 b0 = *reinterpret_cast<const s16x8*>(brow0 + kk);
        s16x8 b1 = *reinterpret_cast<const s16x8*>(brow1 + kk);
        acc00 = __builtin_amdgcn_mfma_f32_16x16x32_bf16(a0, b0, acc00, 0, 0, 0);
        acc01 = __builtin_amdgcn_mfma_f32_16x16x32_bf16(a0, b1, acc01, 0, 0, 0);
        acc10 = __builtin_amdgcn_mfma_f32_16x16x32_bf16(a1, b0, acc10, 0, 0, 0);
        acc11 = __builtin_amdgcn_mfma_f32_16x16x32_bf16(a1, b1, acc11, 0, 0, 0);
    }

    const float kscale = Kin[0] * 4.4642857142857144f;  // 1/0.224 (DATA_SCALING)

    f32x4 accs[2][2] = {{acc00, acc01}, {acc10, acc11}};
#pragma unroll
    for (int mt = 0; mt < 2; ++mt) {
#pragma unroll
        for (int nt = 0; nt < 2; ++nt) {
#pragma unroll
            for (int r = 0; r < 4; ++r) {
                const int ga = base_m + mt * 16 + quad * 4 + r;   // C/D: row = quad*4+reg
                const int gc = base_n + nt * 16 + l16;            // C/D: col = lane&15
                float d2 = sqw[ga] + sqw[gc] - 2.0f * accs[mt][nt][r];
                dist[(size_t)ga * NPAD + gc] = kscale * sqrtf(fmaxf(d2, 0.f));
            }
        }
    }
}

// Kernel 3: per row of prediction: argmax (lowest-index tie-break) then min ratio
__global__ __launch_bounds__(256) void final_kernel(const float* __restrict__ pred,
                                                    const float* __restrict__ dist,
                                                    float* __restrict__ out) {
    const int row = blockIdx.x;
    const int tid = threadIdx.x;
    const int lane = tid & 63, wid = tid >> 6;
    __shared__ float sp[C_CLS];
    __shared__ float sv[4];
    __shared__ int   si[4];

    const float* p = pred + (size_t)row * C_CLS;
    float v = -INFINITY;
    int bi = 0x7fffffff;
    if (tid < 250) {  // 250*4 = 1000, 16B aligned (row stride 4000 B is 16B-multiple)
        float4 x = *reinterpret_cast<const float4*>(p + tid * 4);
        const int c0 = tid * 4;
        sp[c0 + 0] = x.x; sp[c0 + 1] = x.y; sp[c0 + 2] = x.z; sp[c0 + 3] = x.w;
        v = x.x; bi = c0;
        if (x.y > v) { v = x.y; bi = c0 + 1; }
        if (x.z > v) { v = x.z; bi = c0 + 2; }
        if (x.w > v) { v = x.w; bi = c0 + 3; }
    }
#pragma unroll
    for (int off = 32; off > 0; off >>= 1) {
        float ov = __shfl_down(v, off);
        int   oi = __shfl_down(bi, off);
        if (ov > v || (ov == v && oi < bi)) { v = ov; bi = oi; }
    }
    if (lane == 0) { sv[wid] = v; si[wid] = bi; }
    __syncthreads();
    float y0 = sv[0]; int j0 = si[0];
#pragma unroll
    for (int w = 1; w < 4; ++w) {
        if (sv[w] > y0 || (sv[w] == y0 && si[w] < j0)) { y0 = sv[w]; j0 = si[w]; }
    }

    const float* drow = dist + (size_t)j0 * NPAD;
    float rmin = INFINITY;
    for (int c = tid; c < C_CLS; c += 256) {
        if (c == j0) continue;
        float m = y0 - sp[c];
        rmin = fminf(rmin, m / drow[c]);
    }
#pragma unroll
    for (int off = 32; off > 0; off >>= 1) rmin = fminf(rmin, __shfl_down(rmin, off));
    __syncthreads();  // all reads of sv/si for argmax done before reuse
    if (lane == 0) sv[wid] = rmin;
    __syncthreads();
    if (tid == 0) out[row] = fminf(fminf(sv[0], sv[1]), fminf(sv[2], sv[3]));
}

extern "C" void kernel_launch(void* const* d_in, const int* in_sizes, int n_in,
                              void* d_out, int out_size, void* d_ws, size_t ws_size,
                              hipStream_t stream) {
    const float* pred = (const float*)d_in[0];   // (4096, 1000) fp32
    const float* W    = (const float*)d_in[1];   // (1000, 2048) fp32
    const float* K    = (const float*)d_in[2];   // (1,) fp32
    float* out = (float*)d_out;                  // (4096,) fp32

    char* ws = (char*)d_ws;
    unsigned short* Wb = (unsigned short*)ws;                               // 1024*2048*2 = 4 MB
    float* dist = (float*)(ws + (size_t)NPAD * D_DIM * 2);                  // 1024*1024*4 = 4 MB
    float* sqw  = (float*)(ws + (size_t)NPAD * D_DIM * 2 + (size_t)NPAD * NPAD * 4); // 4 KB

    prep_kernel<<<NPAD, 256, 0, stream>>>(W, Wb, sqw);
    dist_kernel<<<dim3(NPAD / 64, NPAD / 64), 256, 0, stream>>>(Wb, sqw, K, dist);
    final_kernel<<<B_ROWS, 256, 0, stream>>>(pred, dist, out);
}